// Round 1
// baseline (135.985 us; speedup 1.0000x reference)
//
#include <hip/hip_runtime.h>

// x: [8, 32, 32, 32, 32] fp32.  Flat = b*2^20 + i*32768 + j*1024 + k*32 + c
// W: [32, 256] row-major (o, 8 sections). Sections:
//   0:x 1:mean_i 2:mean_j 3:mean_k 4:mean_ij 5:mean_ik 6:mean_jk 7:mean_ijk
// out[b,i,j,k,o] = W0.x + B1[b,j,k,o] + B2[b,i,k,o] + A3[b,i,j,o]
//                + A12[b,k,o] + A13[b,j,o] + A23[b,i,o] + A123[b,o] + bias[o]
// R7: fold the three [8192x32]x[32x32] projections (B1,B2,A3) into
// reduce_kernel (rows are already in registers there) -> kills mid's
// latency-starved GEMM phase (120 blocks on 256 CUs), the 12MB S-reread and
// the 8MB S3 round trip (S3 never hits global). segA gets register
// double-buffering (prefetch tile jt+1 before consuming jt). final prefetches
// the invariant tables before the FMA loop. Kernel chain stays 3-deep:
// reduce+proj -> pool (24 blocks) -> final.

static __device__ __forceinline__ float4 f4add(float4 a, float4 b) {
  a.x += b.x; a.y += b.y; a.z += b.z; a.w += b.w; return a;
}

__global__ __launch_bounds__(256) void reduce_kernel(
    const float* __restrict__ x, const float* __restrict__ W,
    float* __restrict__ S1, float* __restrict__ S2,
    float* __restrict__ B1, float* __restrict__ B2,
    float* __restrict__ A3o, float* __restrict__ W0t) {
  __shared__ float sm[11328];
  const int t = threadIdx.x;
  const int seg = blockIdx.x & 1;           // interleave seg0/segA across CUs
  const int idx = blockIdx.x >> 1;
  const int b = idx >> 5, a = idx & 31;

  if (seg == 0) {
    // S1 path: S1[b,a,k,c] = sum_i x[b,i,a,k,c]; then B1 = (S1 row)·W1^T/32
    float* wt = sm;                // W sec1 transposed [c*32+o]
    float* sS = sm + 1024;         // [32][36] padded row stage
    #pragma unroll
    for (int m = 0; m < 4; ++m) {
      const int e = t + 256 * m;
      wt[e] = W[(e & 31) * 256 + 32 + (e >> 5)];
    }
    if (idx == 0) {                // one block publishes W0^T for final
      #pragma unroll
      for (int m = 0; m < 4; ++m) {
        const int e = t + 256 * m;
        W0t[e] = W[(e & 31) * 256 + (e >> 5)];
      }
    }
    const float* base = x + ((size_t)b << 20) + a * 1024 + 4 * t;
    float4 acc = make_float4(0.f, 0.f, 0.f, 0.f);
    #pragma unroll
    for (int i = 0; i < 32; ++i) acc = f4add(acc, *(const float4*)(base + i * 32768));
    ((float4*)(S1 + (size_t)(b * 32 + a) * 1024))[t] = acc;   // pool needs S1
    *(float4*)(sS + (t >> 3) * 36 + 4 * (t & 7)) = acc;       // (k,c0) quad
    __syncthreads();
    // B1[b,a,k,4og..]: thread = (k = t>>3, og = t&7); banks (4k+c)%32 distinct
    const int kk = t >> 3, og = t & 7;
    const float4* wt4 = (const float4*)wt;
    float4 o1 = make_float4(0.f, 0.f, 0.f, 0.f);
    #pragma unroll
    for (int c = 0; c < 32; ++c) {
      const float xv = sS[kk * 36 + c];
      const float4 w = wt4[c * 8 + og];
      o1.x += xv * w.x; o1.y += xv * w.y; o1.z += xv * w.z; o1.w += xv * w.w;
    }
    const float s = 1.f / 32.f;
    o1.x *= s; o1.y *= s; o1.z *= s; o1.w *= s;
    ((float4*)(B1 + (size_t)(b * 32 + a) * 1024))[t] = o1;    // f4 idx = k*8+og = t
  } else {
    // segA: stream slab x[b,a,:,:,:] once -> S2 row, B2 row, A3 row (S3 stays
    // in LDS only). Register double-buffer: prefetch tile jt+1 before consume.
    float* sT  = sm;               // [8][1028] tile
    float* sS3 = sm + 8224;        // [32][33]  sum_k rows
    float* wt2 = sm + 9280;        // W sec2 transposed
    float* wt3 = sm + 10304;       // W sec3 transposed
    #pragma unroll
    for (int m = 0; m < 4; ++m) {
      const int e = t + 256 * m;
      wt2[e] = W[(e & 31) * 256 + 2 * 32 + (e >> 5)];
      wt3[e] = W[(e & 31) * 256 + 3 * 32 + (e >> 5)];
    }
    const float* slab = x + ((size_t)b << 20) + a * 32768;
    float4 accS2 = make_float4(0.f, 0.f, 0.f, 0.f);
    const int jl = t >> 5, cc = t & 31;
    float4 buf[8];
    const float4* src0 = (const float4*)slab;
    #pragma unroll
    for (int m = 0; m < 8; ++m) buf[m] = src0[t + 256 * m];
    for (int jt = 0; jt < 4; ++jt) {
      #pragma unroll
      for (int m = 0; m < 8; ++m) {
        const int q = t + 256 * m;
        float* p = sT + (q >> 8) * 1028 + 4 * (q & 255);
        p[0] = buf[m].x; p[1] = buf[m].y; p[2] = buf[m].z; p[3] = buf[m].w;
      }
      __syncthreads();
      if (jt < 3) {                // loads fly while we consume this tile
        const float4* nxt = (const float4*)(slab + (jt + 1) * 8192);
        #pragma unroll
        for (int m = 0; m < 8; ++m) buf[m] = nxt[t + 256 * m];
      }
      #pragma unroll
      for (int j = 0; j < 8; ++j)
        accS2 = f4add(accS2, *(const float4*)(sT + j * 1028 + 4 * t));
      float s3 = 0.f;
      #pragma unroll
      for (int k = 0; k < 32; ++k) s3 += sT[jl * 1028 + k * 32 + cc];
      sS3[(jt * 8 + jl) * 33 + cc] = s3;   // banks (j+c)%32: 2-way, free
      __syncthreads();
    }
    ((float4*)(S2 + (size_t)(b * 32 + a) * 1024))[t] = accS2;  // pool needs S2
    *(float4*)(sT + (t >> 3) * 36 + 4 * (t & 7)) = accS2;      // reuse sT
    __syncthreads();
    const int kk = t >> 3, og = t & 7;
    const float4* w24 = (const float4*)wt2;
    const float4* w34 = (const float4*)wt3;
    float4 o2 = make_float4(0.f, 0.f, 0.f, 0.f);
    float4 o3 = make_float4(0.f, 0.f, 0.f, 0.f);
    #pragma unroll
    for (int c = 0; c < 32; ++c) {
      const float x2 = sT[kk * 36 + c];
      const float4 w2 = w24[c * 8 + og];
      o2.x += x2 * w2.x; o2.y += x2 * w2.y; o2.z += x2 * w2.z; o2.w += x2 * w2.w;
      const float x3 = sS3[kk * 33 + c];
      const float4 w3 = w34[c * 8 + og];
      o3.x += x3 * w3.x; o3.y += x3 * w3.y; o3.z += x3 * w3.z; o3.w += x3 * w3.w;
    }
    const float s = 1.f / 32.f;
    o2.x *= s; o2.y *= s; o2.z *= s; o2.w *= s;
    o3.x *= s; o3.y *= s; o3.z *= s; o3.w *= s;
    ((float4*)(B2  + (size_t)(b * 32 + a) * 1024))[t] = o2;
    ((float4*)(A3o + (size_t)(b * 32 + a) * 1024))[t] = o3;
  }
}

// pool: second-level pools -> A12/A13/A23/A123 tables. blk = seg*8 + b.
__global__ __launch_bounds__(256) void pool_kernel(
    const float* __restrict__ S1, const float* __restrict__ S2,
    const float* __restrict__ W,
    float* __restrict__ A12g, float* __restrict__ A13g,
    float* __restrict__ A23g, float* __restrict__ A123g) {
  __shared__ float smem[3104];
  const int t = threadIdx.x;
  const int seg = blockIdx.x >> 3, b = blockIdx.x & 7;
  float* sBuf  = smem;           // [32][32] second-level sums
  float* sW    = smem + 1024;    // section 4+seg transposed [c*32+o]
  float* sW7   = smem + 2048;    // section 7 transposed
  float* sS123 = smem + 3072;    // [32]
  const int sec = 4 + seg;

  #pragma unroll
  for (int m = 0; m < 4; ++m) {
    const int e = t + 256 * m, c = e >> 5, o = e & 31;
    sW[e] = W[o * 256 + sec * 32 + c];
    if (seg == 0) sW7[e] = W[o * 256 + 7 * 32 + c];
  }
  const float* Sb = ((seg == 2) ? S2 : S1) + (size_t)b * 32768;
  #pragma unroll
  for (int m = 0; m < 4; ++m) {
    const int e = t + 256 * m, a = e >> 5, c = e & 31;
    float s = 0.f;
    if (seg == 0) {              // S12[k=a,c] = sum_j S1[b,j,a,c]
      for (int j = 0; j < 32; ++j) s += Sb[j * 1024 + a * 32 + c];
    } else {                     // S13/S23[(j|i)=a,c] = sum_k
      for (int k = 0; k < 32; ++k) s += Sb[a * 1024 + k * 32 + c];
    }
    sBuf[e] = s;
  }
  __syncthreads();
  if (seg == 0 && t < 32) {
    float s = 0.f;
    for (int k = 0; k < 32; ++k) s += sBuf[k * 32 + t];
    sS123[t] = s;
  }
  __syncthreads();
  float* Ag = (seg == 0) ? A12g : (seg == 1) ? A13g : A23g;
  #pragma unroll
  for (int m = 0; m < 4; ++m) {
    const int e = t + 256 * m, a = e >> 5, o = e & 31;
    float s = 0.f;
    #pragma unroll
    for (int c = 0; c < 32; ++c) s += sW[c * 32 + o] * sBuf[a * 32 + c];
    Ag[b * 1024 + e] = s * (1.f / 1024.f);
  }
  if (seg == 0 && t < 32) {
    float s = 0.f;
    #pragma unroll
    for (int c = 0; c < 32; ++c) s += sW7[c * 32 + t] * sS123[c];
    A123g[b * 32 + t] = s * (1.f / 32768.f);
  }
}

__global__ __launch_bounds__(256, 4) void final_kernel(
    const float* __restrict__ x, const float* __restrict__ W0t,
    const float* __restrict__ B1, const float* __restrict__ B2,
    const float* __restrict__ A3o, const float* __restrict__ A12g,
    const float* __restrict__ A13g, const float* __restrict__ A23g,
    const float* __restrict__ A123g, const float* __restrict__ bias,
    float* __restrict__ out) {
  __shared__ float xs[256 * 33];
  __shared__ float wt[1024];     // W0 transposed [c*32+o]
  const int t = threadIdx.x;
  const size_t pos0 = (size_t)blockIdx.x * 256;

  const float4* xp4 = (const float4*)(x + pos0 * 32);
  float4 xv[8];
  #pragma unroll
  for (int m = 0; m < 8; ++m) xv[m] = xp4[t + 256 * m];

  // thread = (rg = t>>2: 4 consecutive rows, og = t&3: 8 consecutive outs)
  const int rg = t >> 2, og = t & 3;
  const int lrow0 = 4 * rg;
  const size_t p0 = pos0 + lrow0;
  const int k0 = (int)(p0 & 31), j = (int)(p0 >> 5) & 31,
            i = (int)(p0 >> 10) & 31, b = (int)(p0 >> 15);
  const int oo = og * 8;

  // issue invariant-table loads NOW: latency hides under staging + FMA loop
  const float4* a3p   = (const float4*)(A3o  + ((size_t)((b * 32 + i) * 32 + j)) * 32 + oo);
  const float4* a13p  = (const float4*)(A13g + (size_t)(b * 32 + j) * 32 + oo);
  const float4* a23p  = (const float4*)(A23g + (size_t)(b * 32 + i) * 32 + oo);
  const float4* a123p = (const float4*)(A123g + (size_t)b * 32 + oo);
  const float4* bip   = (const float4*)(bias + oo);
  const float4 va3l = a3p[0],  va3h = a3p[1];
  const float4 vd1l = a13p[0], vd1h = a13p[1];
  const float4 vd2l = a23p[0], vd2h = a23p[1];
  const float4 vd3l = a123p[0], vd3h = a123p[1];
  const float4 vbl  = bip[0],  vbh  = bip[1];

  #pragma unroll
  for (int m = 0; m < 8; ++m) {
    const int q = t + 256 * m;
    float* p = xs + (q >> 3) * 33 + 4 * (q & 7);
    p[0] = xv[m].x; p[1] = xv[m].y; p[2] = xv[m].z; p[3] = xv[m].w;
  }
  #pragma unroll
  for (int m = 0; m < 4; ++m) wt[t + 256 * m] = W0t[t + 256 * m];
  __syncthreads();

  float acc[4][8];
  #pragma unroll
  for (int r = 0; r < 4; ++r)
    #pragma unroll
    for (int u = 0; u < 8; ++u) acc[r][u] = 0.f;

  const float4* wt4 = (const float4*)wt;
  #pragma unroll
  for (int c = 0; c < 32; ++c) {
    const float4 w0 = wt4[c * 8 + og * 2];
    const float4 w1 = wt4[c * 8 + og * 2 + 1];
    #pragma unroll
    for (int r = 0; r < 4; ++r) {
      const float xvv = xs[(lrow0 + r) * 33 + c];
      acc[r][0] += xvv * w0.x; acc[r][1] += xvv * w0.y;
      acc[r][2] += xvv * w0.z; acc[r][3] += xvv * w0.w;
      acc[r][4] += xvv * w1.x; acc[r][5] += xvv * w1.y;
      acc[r][6] += xvv * w1.z; acc[r][7] += xvv * w1.w;
    }
  }

  float inv[8];
  inv[0] = va3l.x + vd1l.x + vd2l.x + vd3l.x + vbl.x;
  inv[1] = va3l.y + vd1l.y + vd2l.y + vd3l.y + vbl.y;
  inv[2] = va3l.z + vd1l.z + vd2l.z + vd3l.z + vbl.z;
  inv[3] = va3l.w + vd1l.w + vd2l.w + vd3l.w + vbl.w;
  inv[4] = va3h.x + vd1h.x + vd2h.x + vd3h.x + vbh.x;
  inv[5] = va3h.y + vd1h.y + vd2h.y + vd3h.y + vbh.y;
  inv[6] = va3h.z + vd1h.z + vd2h.z + vd3h.z + vbh.z;
  inv[7] = va3h.w + vd1h.w + vd2h.w + vd3h.w + vbh.w;

  #pragma unroll
  for (int r = 0; r < 4; ++r) {
    const int k = k0 + r;
    const float* b1  = B1   + ((size_t)((b * 32 + j) * 32 + k)) * 32 + oo;
    const float* b2  = B2   + ((size_t)((b * 32 + i) * 32 + k)) * 32 + oo;
    const float* a12 = A12g + (size_t)(b * 32 + k) * 32 + oo;
    #pragma unroll
    for (int u = 0; u < 8; ++u) acc[r][u] += inv[u] + b1[u] + b2[u] + a12[u];
  }

  #pragma unroll
  for (int r = 0; r < 4; ++r) {
    float4* op = (float4*)(out + (p0 + r) * 32 + oo);
    op[0] = make_float4(acc[r][0], acc[r][1], acc[r][2], acc[r][3]);
    op[1] = make_float4(acc[r][4], acc[r][5], acc[r][6], acc[r][7]);
  }
}

extern "C" void kernel_launch(void* const* d_in, const int* in_sizes, int n_in,
                              void* d_out, int out_size, void* d_ws, size_t ws_size,
                              hipStream_t stream) {
  const float* x    = (const float*)d_in[0];
  const float* W    = (const float*)d_in[1];
  const float* bias = (const float*)d_in[2];
  float* out = (float*)d_out;
  float* ws  = (float*)d_ws;
  float* S1    = ws;                 // 262144
  float* S2    = ws + 262144;        // 262144
  float* B1    = ws + 524288;        // 262144
  float* B2    = ws + 786432;        // 262144
  float* A3o   = ws + 1048576;       // 262144
  float* W0t   = ws + 1310720;       // 1024
  float* A12g  = ws + 1311744;       // 8192
  float* A13g  = ws + 1319936;       // 8192
  float* A23g  = ws + 1328128;       // 8192
  float* A123g = ws + 1336320;       // 256

  reduce_kernel<<<512, 256, 0, stream>>>(x, W, S1, S2, B1, B2, A3o, W0t);
  pool_kernel<<<24, 256, 0, stream>>>(S1, S2, W, A12g, A13g, A23g, A123g);
  final_kernel<<<1024, 256, 0, stream>>>(x, W0t, B1, B2, A3o, A12g, A13g,
                                         A23g, A123g, bias, out);
}

// Round 2
// 109.652 us; speedup vs baseline: 1.2401x; 1.2401x over previous
//
#include <hip/hip_runtime.h>

// x: [8, 32, 32, 32, 32] fp32.  Flat = b*2^20 + i*32768 + j*1024 + k*32 + c
// W: [32, 256] row-major (o, 8 sections). Sections:
//   0:x 1:mean_i 2:mean_j 3:mean_k 4:mean_ij 5:mean_ik 6:mean_jk 7:mean_ijk
// out[b,i,j,k,o] = W0.x + B1[b,j,k,o] + B2[b,i,k,o] + A3[b,i,j,o]
//                + A12[b,k,o] + A13[b,j,o] + A23[b,i,o] + A123[b,o] + bias[o]
// R8: exact R6 structure (112us measured) with ONE change: final_kernel
// store mapping. Old (rg=t>>2,og=t&3) emitted 16B stores covering only half
// of every 32B chunk per instruction -> partial-64B-line RMW at HBM
// (measured: WRITE 108MB vs 33.5 logical, FETCH +17MB). New mapping
// (rg=t>>3: 8 rows, og=t&7: 4 outs) stores one float4 per row with 8
// consecutive lanes covering a full 128B row -> full-line writes only.

static __device__ __forceinline__ float4 f4add(float4 a, float4 b) {
  a.x += b.x; a.y += b.y; a.z += b.z; a.w += b.w; return a;
}

__global__ __launch_bounds__(256) void reduce_kernel(
    const float* __restrict__ x, float* __restrict__ S1,
    float* __restrict__ S2, float* __restrict__ S3) {
  const int t = threadIdx.x;
  if (blockIdx.x < 256) {
    // seg0: S1[b, j=a, k, c] = sum_i x[b,i,a,k,c]; thread owns floats 4t..4t+3
    const int b = blockIdx.x >> 5, a = blockIdx.x & 31;
    const float* base = x + ((size_t)b << 20) + a * 1024 + 4 * t;
    float4 acc = make_float4(0.f, 0.f, 0.f, 0.f);
    #pragma unroll
    for (int i = 0; i < 32; ++i) acc = f4add(acc, *(const float4*)(base + i * 32768));
    ((float4*)(S1 + (size_t)(b * 32 + a) * 1024))[t] = acc;
  } else {
    // segA: block (b, i=a): stream slab x[b,a,:,:,:] once -> S2 row + S3 row
    __shared__ float sT[8 * 1028];   // 8 j-rows of [k,c] (1024) + 4 pad
    const int idx = blockIdx.x - 256;
    const int b = idx >> 5, a = idx & 31;
    const float* slab = x + ((size_t)b << 20) + a * 32768;
    float4 accS2 = make_float4(0.f, 0.f, 0.f, 0.f);
    const int jl = t >> 5, cc = t & 31;      // S3 role: (j_loc, c)
    float* s3row = S3 + (size_t)(b * 32 + a) * 1024;

    for (int jt = 0; jt < 4; ++jt) {
      // load 8 KB tile (j = 8*jt .. +7), fully coalesced float4
      const float4* src4 = (const float4*)(slab + jt * 8192);
      #pragma unroll
      for (int m = 0; m < 8; ++m) {
        const int q = t + 256 * m;           // float4 idx in tile
        const float4 v = src4[q];
        float* p = sT + (q >> 8) * 1028 + 4 * (q & 255);
        p[0] = v.x; p[1] = v.y; p[2] = v.z; p[3] = v.w;
      }
      __syncthreads();
      // S2 accumulate: thread owns (k,c) quad at 4t
      #pragma unroll
      for (int j = 0; j < 8; ++j)
        accS2 = f4add(accS2, *(const float4*)(sT + j * 1028 + 4 * t));
      // S3: thread (jl, cc) sums over k; banks (4*jl + cc + 32k)%32: 2-way free
      float s3 = 0.f;
      #pragma unroll
      for (int k = 0; k < 32; ++k) s3 += sT[jl * 1028 + k * 32 + cc];
      s3row[jt * 256 + t] = s3;              // j = 8*jt + jl, coalesced
      __syncthreads();
    }
    ((float4*)(S2 + (size_t)(b * 32 + a) * 1024))[t] = accS2;
  }
}

// Merged: blocks 0..95 = three [8192x32]x[32x32] GEMMs (B1,B2,A3, scaled 1/32);
//         blocks 96..119 = second-level pools -> A12/A13/A23/A123 tables.
__global__ __launch_bounds__(256) void mid_kernel(
    const float* __restrict__ S1, const float* __restrict__ S2,
    const float* __restrict__ S3, const float* __restrict__ W,
    float* __restrict__ B1, float* __restrict__ B2, float* __restrict__ A3o,
    float* __restrict__ A12g, float* __restrict__ A13g,
    float* __restrict__ A23g, float* __restrict__ A123g,
    float* __restrict__ W0t) {
  __shared__ float smem[9472];
  const int t = threadIdx.x;
  if (blockIdx.x < 96) {
    float* xs = smem;            // [256][33]
    float* wt = smem + 8448;     // W section seg+1 transposed [c*32+o]
    const int seg = blockIdx.x >> 5;
    const int r0 = (blockIdx.x & 31) * 256;
    const float* src = (seg == 0) ? S1 : (seg == 1) ? S2 : S3;
    float* dst = (seg == 0) ? B1 : (seg == 1) ? B2 : A3o;

    const float4* sp4 = (const float4*)(src + (size_t)r0 * 32);
    #pragma unroll
    for (int m = 0; m < 8; ++m) {
      const int q = t + 256 * m;
      const float4 v = sp4[q];
      float* p = xs + (q >> 3) * 33 + 4 * (q & 7);
      p[0] = v.x; p[1] = v.y; p[2] = v.z; p[3] = v.w;
    }
    #pragma unroll
    for (int m = 0; m < 4; ++m) {
      const int e = t + 256 * m;
      wt[e] = W[(e & 31) * 256 + (seg + 1) * 32 + (e >> 5)];
    }
    if (blockIdx.x == 0) {
      #pragma unroll
      for (int m = 0; m < 4; ++m) {
        const int e = t + 256 * m;
        W0t[e] = W[(e & 31) * 256 + (e >> 5)];   // W0t[c*32+o]
      }
    }
    __syncthreads();

    float acc[32];
    #pragma unroll
    for (int o = 0; o < 32; ++o) acc[o] = 0.f;
    const float4* wt4 = (const float4*)wt;
    #pragma unroll
    for (int c = 0; c < 32; ++c) {
      const float xv = xs[t * 33 + c];
      #pragma unroll
      for (int o4 = 0; o4 < 8; ++o4) {
        const float4 w = wt4[c * 8 + o4];
        acc[o4 * 4 + 0] += xv * w.x;
        acc[o4 * 4 + 1] += xv * w.y;
        acc[o4 * 4 + 2] += xv * w.z;
        acc[o4 * 4 + 3] += xv * w.w;
      }
    }
    __syncthreads();
    #pragma unroll
    for (int o = 0; o < 32; ++o) xs[t * 33 + o] = acc[o] * (1.f / 32.f);
    __syncthreads();
    float* op = dst + (size_t)r0 * 32;
    #pragma unroll
    for (int m = 0; m < 32; ++m) {
      const int f = t + 256 * m;
      op[f] = xs[(f >> 5) * 33 + (f & 31)];
    }
  } else {
    // pool: blk = seg*8 + b
    const int blk = blockIdx.x - 96;
    const int seg = blk >> 3, b = blk & 7;
    float* sBuf  = smem;          // [32][32] second-level sums
    float* sW    = smem + 1024;   // section 4+seg transposed [c*32+o]
    float* sW7   = smem + 2048;   // section 7 transposed
    float* sS123 = smem + 3072;   // [32]
    const int sec = 4 + seg;

    #pragma unroll
    for (int m = 0; m < 4; ++m) {
      const int e = t + 256 * m, c = e >> 5, o = e & 31;
      sW[e] = W[o * 256 + sec * 32 + c];
      if (seg == 0) sW7[e] = W[o * 256 + 7 * 32 + c];
    }
    const float* Sb = ((seg == 2) ? S2 : S1) + (size_t)b * 32768;
    #pragma unroll
    for (int m = 0; m < 4; ++m) {
      const int e = t + 256 * m, a = e >> 5, c = e & 31;
      float s = 0.f;
      if (seg == 0) {            // S12[k=a,c] = sum_j S1[b,j,a,c]
        for (int j = 0; j < 32; ++j) s += Sb[j * 1024 + a * 32 + c];
      } else {                   // S13/S23[(j|i)=a,c] = sum_k
        for (int k = 0; k < 32; ++k) s += Sb[a * 1024 + k * 32 + c];
      }
      sBuf[e] = s;
    }
    __syncthreads();
    if (seg == 0 && t < 32) {
      float s = 0.f;
      for (int k = 0; k < 32; ++k) s += sBuf[k * 32 + t];
      sS123[t] = s;
    }
    __syncthreads();
    float* Ag = (seg == 0) ? A12g : (seg == 1) ? A13g : A23g;
    #pragma unroll
    for (int m = 0; m < 4; ++m) {
      const int e = t + 256 * m, a = e >> 5, o = e & 31;
      float s = 0.f;
      #pragma unroll
      for (int c = 0; c < 32; ++c) s += sW[c * 32 + o] * sBuf[a * 32 + c];
      Ag[b * 1024 + e] = s * (1.f / 1024.f);
    }
    if (seg == 0 && t < 32) {
      float s = 0.f;
      #pragma unroll
      for (int c = 0; c < 32; ++c) s += sW7[c * 32 + t] * sS123[c];
      A123g[b * 32 + t] = s * (1.f / 32768.f);
    }
  }
}

__global__ __launch_bounds__(256) void final_kernel(
    const float* __restrict__ x, const float* __restrict__ W0t,
    const float* __restrict__ B1, const float* __restrict__ B2,
    const float* __restrict__ A3o, const float* __restrict__ A12g,
    const float* __restrict__ A13g, const float* __restrict__ A23g,
    const float* __restrict__ A123g, const float* __restrict__ bias,
    float* __restrict__ out) {
  __shared__ float xs[256 * 33];
  __shared__ float wt[1024];     // W0 transposed [c*32+o]
  const int t = threadIdx.x;
  const size_t pos0 = (size_t)blockIdx.x * 256;

  const float4* xp4 = (const float4*)(x + pos0 * 32);
  #pragma unroll
  for (int m = 0; m < 8; ++m) {
    const int q = t + 256 * m;
    const float4 v = xp4[q];
    float* p = xs + (q >> 3) * 33 + 4 * (q & 7);
    p[0] = v.x; p[1] = v.y; p[2] = v.z; p[3] = v.w;
  }
  #pragma unroll
  for (int m = 0; m < 4; ++m) wt[t + 256 * m] = W0t[t + 256 * m];
  __syncthreads();

  // thread = (rg = t>>3: 8 consecutive rows, og = t&7: 4 consecutive outs)
  // store: one float4 per row; 8 consecutive lanes cover a full 128B row ->
  // every wave store instruction touches only FULL 64B lines (no RMW).
  const int rg = t >> 3, og = t & 7;
  const int lrow0 = 8 * rg;
  const size_t p0 = pos0 + lrow0;
  const int k0 = (int)(p0 & 31), j = (int)(p0 >> 5) & 31,
            i = (int)(p0 >> 10) & 31, b = (int)(p0 >> 15);
  const int oo = og * 4;

  float acc[8][4];
  #pragma unroll
  for (int r = 0; r < 8; ++r)
    #pragma unroll
    for (int u = 0; u < 4; ++u) acc[r][u] = 0.f;

  const float4* wt4 = (const float4*)wt;
  #pragma unroll
  for (int c = 0; c < 32; ++c) {
    const float4 w = wt4[c * 8 + og];
    #pragma unroll
    for (int r = 0; r < 8; ++r) {
      const float xv = xs[(lrow0 + r) * 33 + c];
      acc[r][0] += xv * w.x; acc[r][1] += xv * w.y;
      acc[r][2] += xv * w.z; acc[r][3] += xv * w.w;
    }
  }

  const float4 va3  = *(const float4*)(A3o  + ((size_t)((b * 32 + i) * 32 + j)) * 32 + oo);
  const float4 va13 = *(const float4*)(A13g + (size_t)(b * 32 + j) * 32 + oo);
  const float4 va23 = *(const float4*)(A23g + (size_t)(b * 32 + i) * 32 + oo);
  const float4 va123= *(const float4*)(A123g + (size_t)b * 32 + oo);
  const float4 vbi  = *(const float4*)(bias + oo);
  float inv[4];
  inv[0] = va3.x + va13.x + va23.x + va123.x + vbi.x;
  inv[1] = va3.y + va13.y + va23.y + va123.y + vbi.y;
  inv[2] = va3.z + va13.z + va23.z + va123.z + vbi.z;
  inv[3] = va3.w + va13.w + va23.w + va123.w + vbi.w;

  #pragma unroll
  for (int r = 0; r < 8; ++r) {
    const int k = k0 + r;
    const float4 vb1 = *(const float4*)(B1 + ((size_t)((b * 32 + j) * 32 + k)) * 32 + oo);
    const float4 vb2 = *(const float4*)(B2 + ((size_t)((b * 32 + i) * 32 + k)) * 32 + oo);
    const float4 v12 = *(const float4*)(A12g + (size_t)(b * 32 + k) * 32 + oo);
    acc[r][0] += inv[0] + vb1.x + vb2.x + v12.x;
    acc[r][1] += inv[1] + vb1.y + vb2.y + v12.y;
    acc[r][2] += inv[2] + vb1.z + vb2.z + v12.z;
    acc[r][3] += inv[3] + vb1.w + vb2.w + v12.w;
  }

  #pragma unroll
  for (int r = 0; r < 8; ++r) {
    *(float4*)(out + (p0 + r) * 32 + oo) =
        make_float4(acc[r][0], acc[r][1], acc[r][2], acc[r][3]);
  }
}

extern "C" void kernel_launch(void* const* d_in, const int* in_sizes, int n_in,
                              void* d_out, int out_size, void* d_ws, size_t ws_size,
                              hipStream_t stream) {
  const float* x    = (const float*)d_in[0];
  const float* W    = (const float*)d_in[1];
  const float* bias = (const float*)d_in[2];
  float* out = (float*)d_out;
  float* ws  = (float*)d_ws;
  float* S1    = ws;                // 262144
  float* S2    = ws + 262144;
  float* S3    = ws + 524288;
  float* B1    = ws + 786432;
  float* B2    = ws + 1048576;
  float* A3o   = ws + 1310720;
  float* W0t   = ws + 1572864;      // 1024
  float* A12g  = ws + 1573888;      // 8192
  float* A13g  = ws + 1582080;      // 8192
  float* A23g  = ws + 1590272;      // 8192
  float* A123g = ws + 1598464;      // 256

  reduce_kernel<<<512, 256, 0, stream>>>(x, S1, S2, S3);
  mid_kernel<<<120, 256, 0, stream>>>(S1, S2, S3, W, B1, B2, A3o,
                                      A12g, A13g, A23g, A123g, W0t);
  final_kernel<<<1024, 256, 0, stream>>>(x, W0t, B1, B2, A3o, A12g, A13g,
                                         A23g, A123g, bias, out);
}

// Round 4
// 107.369 us; speedup vs baseline: 1.2665x; 1.0213x over previous
//
#include <hip/hip_runtime.h>

// x: [8, 32, 32, 32, 32] fp32.  Flat = b*2^20 + i*32768 + j*1024 + k*32 + c
// W: [32, 256] row-major (o, 8 sections). Sections:
//   0:x 1:mean_i 2:mean_j 3:mean_k 4:mean_ij 5:mean_ik 6:mean_jk 7:mean_ijk
// out[b,i,j,k,o] = W0.x + B1[b,j,k,o] + B2[b,i,k,o] + A3[b,i,j,o]
//                + A12[b,k,o] + A13[b,j,o] + A23[b,i,o] + A123[b,o] + bias[o]
// R10: identical to R9 (which never ran: container infra failure) except
// final_kernel uses plain __launch_bounds__(256) — LDS (21KB) already caps
// residency at 7 blocks/CU, so the min-waves arg was redundant.
// R9 rationale: final_kernel is LATENCY-bound (R1: 46us, VALU 9%, HBM 45%,
// occ 33%; R2: 2.4x traffic cut bought only 2.3us). 128 rows/block (2048
// blocks), half the per-block dependence chain, invariant table loads
// issued before the sync. reduce/mid identical to R8 (112us-verified).

static __device__ __forceinline__ float4 f4add(float4 a, float4 b) {
  a.x += b.x; a.y += b.y; a.z += b.z; a.w += b.w; return a;
}

__global__ __launch_bounds__(256) void reduce_kernel(
    const float* __restrict__ x, float* __restrict__ S1,
    float* __restrict__ S2, float* __restrict__ S3) {
  const int t = threadIdx.x;
  if (blockIdx.x < 256) {
    // seg0: S1[b, j=a, k, c] = sum_i x[b,i,a,k,c]; thread owns floats 4t..4t+3
    const int b = blockIdx.x >> 5, a = blockIdx.x & 31;
    const float* base = x + ((size_t)b << 20) + a * 1024 + 4 * t;
    float4 acc = make_float4(0.f, 0.f, 0.f, 0.f);
    #pragma unroll
    for (int i = 0; i < 32; ++i) acc = f4add(acc, *(const float4*)(base + i * 32768));
    ((float4*)(S1 + (size_t)(b * 32 + a) * 1024))[t] = acc;
  } else {
    // segA: block (b, i=a): stream slab x[b,a,:,:,:] once -> S2 row + S3 row
    __shared__ float sT[8 * 1028];   // 8 j-rows of [k,c] (1024) + 4 pad
    const int idx = blockIdx.x - 256;
    const int b = idx >> 5, a = idx & 31;
    const float* slab = x + ((size_t)b << 20) + a * 32768;
    float4 accS2 = make_float4(0.f, 0.f, 0.f, 0.f);
    const int jl = t >> 5, cc = t & 31;      // S3 role: (j_loc, c)
    float* s3row = S3 + (size_t)(b * 32 + a) * 1024;

    for (int jt = 0; jt < 4; ++jt) {
      // load 8 KB tile (j = 8*jt .. +7), fully coalesced float4
      const float4* src4 = (const float4*)(slab + jt * 8192);
      #pragma unroll
      for (int m = 0; m < 8; ++m) {
        const int q = t + 256 * m;           // float4 idx in tile
        const float4 v = src4[q];
        float* p = sT + (q >> 8) * 1028 + 4 * (q & 255);
        p[0] = v.x; p[1] = v.y; p[2] = v.z; p[3] = v.w;
      }
      __syncthreads();
      // S2 accumulate: thread owns (k,c) quad at 4t
      #pragma unroll
      for (int j = 0; j < 8; ++j)
        accS2 = f4add(accS2, *(const float4*)(sT + j * 1028 + 4 * t));
      // S3: thread (jl, cc) sums over k; banks (4*jl + cc + 32k)%32: 2-way free
      float s3 = 0.f;
      #pragma unroll
      for (int k = 0; k < 32; ++k) s3 += sT[jl * 1028 + k * 32 + cc];
      s3row[jt * 256 + t] = s3;              // j = 8*jt + jl, coalesced
      __syncthreads();
    }
    ((float4*)(S2 + (size_t)(b * 32 + a) * 1024))[t] = accS2;
  }
}

// Merged: blocks 0..95 = three [8192x32]x[32x32] GEMMs (B1,B2,A3, scaled 1/32);
//         blocks 96..119 = second-level pools -> A12/A13/A23/A123 tables.
__global__ __launch_bounds__(256) void mid_kernel(
    const float* __restrict__ S1, const float* __restrict__ S2,
    const float* __restrict__ S3, const float* __restrict__ W,
    float* __restrict__ B1, float* __restrict__ B2, float* __restrict__ A3o,
    float* __restrict__ A12g, float* __restrict__ A13g,
    float* __restrict__ A23g, float* __restrict__ A123g,
    float* __restrict__ W0t) {
  __shared__ float smem[9472];
  const int t = threadIdx.x;
  if (blockIdx.x < 96) {
    float* xs = smem;            // [256][33]
    float* wt = smem + 8448;     // W section seg+1 transposed [c*32+o]
    const int seg = blockIdx.x >> 5;
    const int r0 = (blockIdx.x & 31) * 256;
    const float* src = (seg == 0) ? S1 : (seg == 1) ? S2 : S3;
    float* dst = (seg == 0) ? B1 : (seg == 1) ? B2 : A3o;

    const float4* sp4 = (const float4*)(src + (size_t)r0 * 32);
    #pragma unroll
    for (int m = 0; m < 8; ++m) {
      const int q = t + 256 * m;
      const float4 v = sp4[q];
      float* p = xs + (q >> 3) * 33 + 4 * (q & 7);
      p[0] = v.x; p[1] = v.y; p[2] = v.z; p[3] = v.w;
    }
    #pragma unroll
    for (int m = 0; m < 4; ++m) {
      const int e = t + 256 * m;
      wt[e] = W[(e & 31) * 256 + (seg + 1) * 32 + (e >> 5)];
    }
    if (blockIdx.x == 0) {
      #pragma unroll
      for (int m = 0; m < 4; ++m) {
        const int e = t + 256 * m;
        W0t[e] = W[(e & 31) * 256 + (e >> 5)];   // W0t[c*32+o]
      }
    }
    __syncthreads();

    float acc[32];
    #pragma unroll
    for (int o = 0; o < 32; ++o) acc[o] = 0.f;
    const float4* wt4 = (const float4*)wt;
    #pragma unroll
    for (int c = 0; c < 32; ++c) {
      const float xv = xs[t * 33 + c];
      #pragma unroll
      for (int o4 = 0; o4 < 8; ++o4) {
        const float4 w = wt4[c * 8 + o4];
        acc[o4 * 4 + 0] += xv * w.x;
        acc[o4 * 4 + 1] += xv * w.y;
        acc[o4 * 4 + 2] += xv * w.z;
        acc[o4 * 4 + 3] += xv * w.w;
      }
    }
    __syncthreads();
    #pragma unroll
    for (int o = 0; o < 32; ++o) xs[t * 33 + o] = acc[o] * (1.f / 32.f);
    __syncthreads();
    float* op = dst + (size_t)r0 * 32;
    #pragma unroll
    for (int m = 0; m < 32; ++m) {
      const int f = t + 256 * m;
      op[f] = xs[(f >> 5) * 33 + (f & 31)];
    }
  } else {
    // pool: blk = seg*8 + b
    const int blk = blockIdx.x - 96;
    const int seg = blk >> 3, b = blk & 7;
    float* sBuf  = smem;          // [32][32] second-level sums
    float* sW    = smem + 1024;   // section 4+seg transposed [c*32+o]
    float* sW7   = smem + 2048;   // section 7 transposed
    float* sS123 = smem + 3072;   // [32]
    const int sec = 4 + seg;

    #pragma unroll
    for (int m = 0; m < 4; ++m) {
      const int e = t + 256 * m, c = e >> 5, o = e & 31;
      sW[e] = W[o * 256 + sec * 32 + c];
      if (seg == 0) sW7[e] = W[o * 256 + 7 * 32 + c];
    }
    const float* Sb = ((seg == 2) ? S2 : S1) + (size_t)b * 32768;
    #pragma unroll
    for (int m = 0; m < 4; ++m) {
      const int e = t + 256 * m, a = e >> 5, c = e & 31;
      float s = 0.f;
      if (seg == 0) {            // S12[k=a,c] = sum_j S1[b,j,a,c]
        for (int j = 0; j < 32; ++j) s += Sb[j * 1024 + a * 32 + c];
      } else {                   // S13/S23[(j|i)=a,c] = sum_k
        for (int k = 0; k < 32; ++k) s += Sb[a * 1024 + k * 32 + c];
      }
      sBuf[e] = s;
    }
    __syncthreads();
    if (seg == 0 && t < 32) {
      float s = 0.f;
      for (int k = 0; k < 32; ++k) s += sBuf[k * 32 + t];
      sS123[t] = s;
    }
    __syncthreads();
    float* Ag = (seg == 0) ? A12g : (seg == 1) ? A13g : A23g;
    #pragma unroll
    for (int m = 0; m < 4; ++m) {
      const int e = t + 256 * m, a = e >> 5, o = e & 31;
      float s = 0.f;
      #pragma unroll
      for (int c = 0; c < 32; ++c) s += sW[c * 32 + o] * sBuf[a * 32 + c];
      Ag[b * 1024 + e] = s * (1.f / 1024.f);
    }
    if (seg == 0 && t < 32) {
      float s = 0.f;
      #pragma unroll
      for (int c = 0; c < 32; ++c) s += sW7[c * 32 + t] * sS123[c];
      A123g[b * 32 + t] = s * (1.f / 32768.f);
    }
  }
}

// 128 rows/block, 2048 blocks. LDS = 128*33 + 1024 floats = 20.9 KB ->
// 7 blocks/CU (28 waves/CU). Thread = (rg=t>>3: 4 rows, og=t&7: 4 outs).
__global__ __launch_bounds__(256) void final_kernel(
    const float* __restrict__ x, const float* __restrict__ W0t,
    const float* __restrict__ B1, const float* __restrict__ B2,
    const float* __restrict__ A3o, const float* __restrict__ A12g,
    const float* __restrict__ A13g, const float* __restrict__ A23g,
    const float* __restrict__ A123g, const float* __restrict__ bias,
    float* __restrict__ out) {
  __shared__ float xs[128 * 33];
  __shared__ float wt[1024];     // W0 transposed [c*32+o]
  const int t = threadIdx.x;
  const size_t pos0 = (size_t)blockIdx.x * 128;

  const int rg = t >> 3, og = t & 7;
  const int lrow0 = 4 * rg;
  const size_t p0 = pos0 + lrow0;
  const int k0 = (int)(p0 & 31), j = (int)(p0 >> 5) & 31,
            i = (int)(p0 >> 10) & 31, b = (int)(p0 >> 15);
  const int oo = og * 4;

  // issue row-invariant table loads first: latency hides under stage+sync+FMA
  const float4 va3  = *(const float4*)(A3o  + ((size_t)((b * 32 + i) * 32 + j)) * 32 + oo);
  const float4 va13 = *(const float4*)(A13g + (size_t)(b * 32 + j) * 32 + oo);
  const float4 va23 = *(const float4*)(A23g + (size_t)(b * 32 + i) * 32 + oo);
  const float4 va123= *(const float4*)(A123g + (size_t)b * 32 + oo);
  const float4 vbi  = *(const float4*)(bias + oo);

  // stage x tile: 128 rows * 32c = 1024 float4, 4 per thread
  const float4* xp4 = (const float4*)(x + pos0 * 32);
  #pragma unroll
  for (int m = 0; m < 4; ++m) {
    const int q = t + 256 * m;
    const float4 v = xp4[q];
    float* p = xs + (q >> 3) * 33 + 4 * (q & 7);
    p[0] = v.x; p[1] = v.y; p[2] = v.z; p[3] = v.w;
  }
  #pragma unroll
  for (int m = 0; m < 4; ++m) wt[t + 256 * m] = W0t[t + 256 * m];
  __syncthreads();

  float acc[4][4];
  #pragma unroll
  for (int r = 0; r < 4; ++r)
    #pragma unroll
    for (int u = 0; u < 4; ++u) acc[r][u] = 0.f;

  const float4* wt4 = (const float4*)wt;
  #pragma unroll
  for (int c = 0; c < 32; ++c) {
    const float4 w = wt4[c * 8 + og];
    #pragma unroll
    for (int r = 0; r < 4; ++r) {
      const float xv = xs[(lrow0 + r) * 33 + c];
      acc[r][0] += xv * w.x; acc[r][1] += xv * w.y;
      acc[r][2] += xv * w.z; acc[r][3] += xv * w.w;
    }
  }

  float inv[4];
  inv[0] = va3.x + va13.x + va23.x + va123.x + vbi.x;
  inv[1] = va3.y + va13.y + va23.y + va123.y + vbi.y;
  inv[2] = va3.z + va13.z + va23.z + va123.z + vbi.z;
  inv[3] = va3.w + va13.w + va23.w + va123.w + vbi.w;

  #pragma unroll
  for (int r = 0; r < 4; ++r) {
    const int k = k0 + r;
    const float4 vb1 = *(const float4*)(B1 + ((size_t)((b * 32 + j) * 32 + k)) * 32 + oo);
    const float4 vb2 = *(const float4*)(B2 + ((size_t)((b * 32 + i) * 32 + k)) * 32 + oo);
    const float4 v12 = *(const float4*)(A12g + (size_t)(b * 32 + k) * 32 + oo);
    acc[r][0] += inv[0] + vb1.x + vb2.x + v12.x;
    acc[r][1] += inv[1] + vb1.y + vb2.y + v12.y;
    acc[r][2] += inv[2] + vb1.z + vb2.z + v12.z;
    acc[r][3] += inv[3] + vb1.w + vb2.w + v12.w;
  }

  #pragma unroll
  for (int r = 0; r < 4; ++r) {
    *(float4*)(out + (p0 + r) * 32 + oo) =
        make_float4(acc[r][0], acc[r][1], acc[r][2], acc[r][3]);
  }
}

extern "C" void kernel_launch(void* const* d_in, const int* in_sizes, int n_in,
                              void* d_out, int out_size, void* d_ws, size_t ws_size,
                              hipStream_t stream) {
  const float* x    = (const float*)d_in[0];
  const float* W    = (const float*)d_in[1];
  const float* bias = (const float*)d_in[2];
  float* out = (float*)d_out;
  float* ws  = (float*)d_ws;
  float* S1    = ws;                // 262144
  float* S2    = ws + 262144;
  float* S3    = ws + 524288;
  float* B1    = ws + 786432;
  float* B2    = ws + 1048576;
  float* A3o   = ws + 1310720;
  float* W0t   = ws + 1572864;      // 1024
  float* A12g  = ws + 1573888;      // 8192
  float* A13g  = ws + 1582080;      // 8192
  float* A23g  = ws + 1590272;      // 8192
  float* A123g = ws + 1598464;      // 256

  reduce_kernel<<<512, 256, 0, stream>>>(x, S1, S2, S3);
  mid_kernel<<<120, 256, 0, stream>>>(S1, S2, S3, W, B1, B2, A3o,
                                      A12g, A13g, A23g, A123g, W0t);
  final_kernel<<<2048, 256, 0, stream>>>(x, W0t, B1, B2, A3o, A12g, A13g,
                                         A23g, A123g, bias, out);
}